// Round 8
// baseline (44.018 us; speedup 1.0000x reference)
//
#include <hip/hip_runtime.h>
#include <math.h>

#define NN 32
#define CC 32
#define MM 196
#define OO 10
#define RECSZ 192       // per-(it,n,c) record: AW[0..160), S[160..170), T[170..180)
#define NEPS 1e-6f
#define NV_OFF 589824   // rec area: 3*NN*CC*RECSZ floats; nv area: NN*CC*OO*MM floats

#define LPS 20          // lpM row stride (floats): 80B, 16B-aligned
#define RTS 209         // rT/pT row stride: odd -> o*RTS bank-spread for paired b32 reads

// rec(it,n,c) = ws + ((it*NN+n)*CC+c)*RECSZ
// nv(n,c)     = ws + NV_OFF + (n*CC+c)*OO*MM     layout [o][m]

__device__ __forceinline__ float rs_step(float lo, float hi, int mask, bool take_hi) {
    // reduce-scatter exchange: I keep (take_hi?hi:lo); partner sends its copy of my kept idx
    float send = take_hi ? lo : hi;
    float recv = __shfl_xor(send, mask);
    return (take_hi ? hi : lo) + recv;
}

template<int IT>   // IT=0: direct V path, gv=g, r*=0.1 ; IT=1,2: factored path; IT=2 adds T
__global__ __launch_bounds__(256, 4) void accum_kernel(
    const float* __restrict__ l, const float* __restrict__ g,
    const float* __restrict__ weight, float* __restrict__ ws)
{
    const int n = blockIdx.x >> 5, c = blockIdx.x & 31, tid = threadIdx.x;
    __shared__ __align__(16) float Wl[160], gvl[160], Wg[160];
    __shared__ float Ablk[160], ggs[16], Ss[16];
    __shared__ __align__(16) float lpM[208 * LPS];   // m-major: lpM[m*LPS + ij]
    __shared__ float rT[OO * RTS];                   // rT[o*RTS + m]
    __shared__ float pT[OO * RTS];                   // IT2: r*||V||^2 (LDS)

    if (tid < 160) Wl[tid] = weight[c * 160 + tid];
    // zero-fill pad rows m=196..207 so chunk 15 contributes zeros
    if (tid < 192) lpM[(196 + (tid >> 4)) * LPS + (tid & 15)] = 0.f;
    if (tid < 120) {
        rT[(tid / 12) * RTS + 196 + (tid % 12)] = 0.f;
        if (IT == 2) pT[(tid / 12) * RTS + 196 + (tid % 12)] = 0.f;
    }

    if constexpr (IT == 0) {
        if (tid < 160) gvl[tid] = g[n * 160 + tid];
    } else {
        // inline reduce of previous iteration's records for this n (L2-hot)
        const float* base = ws + ((size_t)((IT - 1) * NN + n) * CC) * RECSZ;
        if (tid < 160) {
            float u = 0.f;
            for (int cc2 = 0; cc2 < CC; ++cc2) u += base[cc2 * RECSZ + tid];
            Ablk[tid] = u;                                  // UV (temp)
        } else if (tid < 170) {
            float s = 0.f;
            for (int cc2 = 0; cc2 < CC; ++cc2) s += base[cc2 * RECSZ + 160 + (tid - 160)];
            Ss[tid - 160] = s + NEPS;
        }
        __syncthreads();
        if (tid < 160) gvl[tid] = Ablk[tid] / Ss[tid >> 4]; // gv = UV/(S+EPS)
        __syncthreads();
        if (tid < 160) {                                    // Wg[o,i,j] = sum_k W[o,j,k]*gv[o,i,k]
            const int o = tid >> 4, i = (tid >> 2) & 3, j = tid & 3;
            float acc = 0.f;
            #pragma unroll
            for (int k = 0; k < 4; ++k)
                acc = fmaf(Wl[o * 16 + j * 4 + k], gvl[o * 16 + i * 4 + k], acc);
            Wg[tid] = acc;
        } else if (tid >= 160 && tid < 170) {
            const int o = tid - 160;
            float s = 0.f;
            #pragma unroll
            for (int e = 0; e < 16; ++e) s = fmaf(gvl[o * 16 + e], gvl[o * 16 + e], s);
            ggs[o] = s;                                     // ||gv_o||^2
        }
    }

    const bool act = tid < MM;
    float lp[16];
    if (act) {
        const float* lbase = l + ((size_t)(n * CC + c)) * (16 * MM) + tid;
        #pragma unroll
        for (int dd = 0; dd < 16; ++dd) lp[dd] = lbase[dd * MM];   // coalesced
        float4* dst = (float4*)&lpM[tid * LPS];
        dst[0] = make_float4(lp[0],  lp[1],  lp[2],  lp[3]);
        dst[1] = make_float4(lp[4],  lp[5],  lp[6],  lp[7]);
        dst[2] = make_float4(lp[8],  lp[9],  lp[10], lp[11]);
        dst[3] = make_float4(lp[12], lp[13], lp[14], lp[15]);
    }
    __syncthreads();   // gvl/Wg/ggs/lpM(+pads) ready

    float* nvg = ws + NV_OFF + (size_t)(n * CC + c) * (OO * MM);
    if (act) {
        const int m = tid;
        float rn[OO], nvl[OO];
        float rd = 0.f;
        #pragma unroll
        for (int o = 0; o < OO; ++o) {
            float dist;
            if constexpr (IT == 0) {
                const float4* wrow = (const float4*)&Wl[o * 16];
                float4 w0 = wrow[0], w1 = wrow[1], w2 = wrow[2], w3 = wrow[3];  // w_j[k]
                const float4* grow = (const float4*)&gvl[o * 16];
                float4 gv0 = grow[0], gv1 = grow[1], gv2 = grow[2], gv3 = grow[3]; // g_i[k]
                float nvv = 0.f; dist = 0.f;
                #pragma unroll
                for (int i = 0; i < 4; ++i) {
                    const float li0 = lp[i * 4 + 0], li1 = lp[i * 4 + 1];
                    const float li2 = lp[i * 4 + 2], li3 = lp[i * 4 + 3];
                    float4 gi = (i == 0) ? gv0 : (i == 1) ? gv1 : (i == 2) ? gv2 : gv3;
                    float vx = li0 * w0.x; vx = fmaf(li1, w1.x, vx);
                    vx = fmaf(li2, w2.x, vx); vx = fmaf(li3, w3.x, vx);
                    float vy = li0 * w0.y; vy = fmaf(li1, w1.y, vy);
                    vy = fmaf(li2, w2.y, vy); vy = fmaf(li3, w3.y, vy);
                    float vz = li0 * w0.z; vz = fmaf(li1, w1.z, vz);
                    vz = fmaf(li2, w2.z, vz); vz = fmaf(li3, w3.z, vz);
                    float vw = li0 * w0.w; vw = fmaf(li1, w1.w, vw);
                    vw = fmaf(li2, w2.w, vw); vw = fmaf(li3, w3.w, vw);
                    nvv = fmaf(vx, vx, nvv); nvv = fmaf(vy, vy, nvv);
                    nvv = fmaf(vz, vz, nvv); nvv = fmaf(vw, vw, nvv);
                    float dx = vx - gi.x, dy = vy - gi.y, dz = vz - gi.z, dw = vw - gi.w;
                    dist = fmaf(dx, dx, dist); dist = fmaf(dy, dy, dist);
                    dist = fmaf(dz, dz, dist); dist = fmaf(dw, dw, dist);
                }
                nvg[o * MM + m] = nvv;      // persist ||V||^2 for iters 1-2
            } else {
                const float nvv = nvg[o * MM + m];   // coalesced reload
                nvl[o] = nvv;
                const float4* wg4 = (const float4*)&Wg[o * 16];
                float4 w0 = wg4[0], w1 = wg4[1], w2 = wg4[2], w3 = wg4[3];
                float dot = 0.f;
                dot = fmaf(lp[0],  w0.x, dot); dot = fmaf(lp[1],  w0.y, dot);
                dot = fmaf(lp[2],  w0.z, dot); dot = fmaf(lp[3],  w0.w, dot);
                dot = fmaf(lp[4],  w1.x, dot); dot = fmaf(lp[5],  w1.y, dot);
                dot = fmaf(lp[6],  w1.z, dot); dot = fmaf(lp[7],  w1.w, dot);
                dot = fmaf(lp[8],  w2.x, dot); dot = fmaf(lp[9],  w2.y, dot);
                dot = fmaf(lp[10], w2.z, dot); dot = fmaf(lp[11], w2.w, dot);
                dot = fmaf(lp[12], w3.x, dot); dot = fmaf(lp[13], w3.y, dot);
                dot = fmaf(lp[14], w3.z, dot); dot = fmaf(lp[15], w3.w, dot);
                dist = fmaxf(nvv - 2.f * dot + ggs[o], 0.f);   // ||V-gv||^2, guarded
            }
            rn[o] = dist + NEPS;
            rd += 1.0f / rn[o];
        }
        #pragma unroll
        for (int o = 0; o < OO; ++o) {
            float t = 1.0f / (rn[o] * rd);
            float r = t * t;
            if constexpr (IT == 0) r *= 0.1f;      // a_in / N_CLASSES
            rT[o * RTS + m] = r;
            if constexpr (IT == 2) pT[o * RTS + m] = r * nvl[o];
        }
    }
    __syncthreads();   // rT (and pT) ready

    float* rec = ws + ((size_t)(IT * NN + n) * CC + c) * RECSZ;
    // ---- o-pair chunked reduction: thread (op,ch) does 13 m's x 16 ij x 2 o's ----
    if (tid < 80) {
        const int op = tid >> 4, ch = tid & 15;
        const int o0 = op * 2, o1 = o0 + 1;
        const int m0 = ch * 13;
        float A0[16], A1[16];
        #pragma unroll
        for (int q = 0; q < 16; ++q) { A0[q] = 0.f; A1[q] = 0.f; }
        float s0 = 0.f, s1 = 0.f, t0 = 0.f, t1 = 0.f;
        #pragma unroll
        for (int i = 0; i < 13; ++i) {
            const int m = m0 + i;
            const float r0 = rT[o0 * RTS + m];
            const float r1 = rT[o1 * RTS + m];
            const float4* lq = (const float4*)&lpM[m * LPS];
            float lv[16];
            *(float4*)&lv[0]  = lq[0];
            *(float4*)&lv[4]  = lq[1];
            *(float4*)&lv[8]  = lq[2];
            *(float4*)&lv[12] = lq[3];
            #pragma unroll
            for (int q = 0; q < 16; ++q) {
                A0[q] = fmaf(r0, lv[q], A0[q]);
                A1[q] = fmaf(r1, lv[q], A1[q]);
            }
            s0 += r0; s1 += r1;
            if constexpr (IT == 2) {
                t0 += pT[o0 * RTS + m];
                t1 += pT[o1 * RTS + m];
            }
        }
        // ---- 16-lane reduce-scatter per o: lane ch ends holding A[o][ch] ----
        const int p = ch;
        const bool h1 = (p & 1), h2 = (p & 2), h4 = (p & 4), h8 = (p & 8);
        auto rs16 = [&](const float* a) -> float {
            float b0 = rs_step(a[0],  a[1],  1, h1), b1 = rs_step(a[2],  a[3],  1, h1);
            float b2 = rs_step(a[4],  a[5],  1, h1), b3 = rs_step(a[6],  a[7],  1, h1);
            float b4 = rs_step(a[8],  a[9],  1, h1), b5 = rs_step(a[10], a[11], 1, h1);
            float b6 = rs_step(a[12], a[13], 1, h1), b7 = rs_step(a[14], a[15], 1, h1);
            float c0 = rs_step(b0, b1, 2, h2), c1 = rs_step(b2, b3, 2, h2);
            float c2 = rs_step(b4, b5, 2, h2), c3 = rs_step(b6, b7, 2, h2);
            float d0 = rs_step(c0, c1, 4, h4), d1 = rs_step(c2, c3, 4, h4);
            return rs_step(d0, d1, 8, h8);
        };
        const float e0 = rs16(A0), e1 = rs16(A1);
        #pragma unroll
        for (int mk = 1; mk <= 8; mk <<= 1) {
            s0 += __shfl_xor(s0, mk);
            s1 += __shfl_xor(s1, mk);
            if constexpr (IT == 2) {
                t0 += __shfl_xor(t0, mk);
                t1 += __shfl_xor(t1, mk);
            }
        }
        Ablk[o0 * 16 + p] = e0;
        Ablk[o1 * 16 + p] = e1;
        if (p == 0) {
            rec[160 + o0] = s0;
            rec[160 + o1] = s1;
            if constexpr (IT == 2) {
                rec[170 + o0] = t0;
                rec[170 + o1] = t1;
            }
        }
    }
    __syncthreads();   // Ablk ready
    if (tid < 160) {   // AW = A @ W[c,o]
        const int o = tid >> 4, ik = tid & 15, i = ik >> 2, k = ik & 3;
        float aw = 0.f;
        #pragma unroll
        for (int j = 0; j < 4; ++j)
            aw = fmaf(Ablk[o * 16 + i * 4 + j], Wl[o * 16 + j * 4 + k], aw);
        rec[tid] = aw;
    }
}

__global__ __launch_bounds__(256) void finalize_kernel(
    const float* __restrict__ beta_a, float* __restrict__ out, const float* __restrict__ ws)
{
    const int n = blockIdx.x, tid = threadIdx.x;
    __shared__ float Sred[OO], Tred[OO], gvl[160];

    const float* base = ws + ((size_t)(2 * NN + n) * CC) * RECSZ;
    float uacc = 0.f;
    if (tid < 160) {
        for (int cc2 = 0; cc2 < CC; ++cc2) uacc += base[cc2 * RECSZ + tid];
    } else if (tid < 170) {
        const int o = tid - 160;
        float s = 0.f, t = 0.f;
        for (int cc2 = 0; cc2 < CC; ++cc2) {
            s += base[cc2 * RECSZ + 160 + o];
            t += base[cc2 * RECSZ + 170 + o];
        }
        Sred[o] = s + NEPS;
        Tred[o] = t;
    }
    __syncthreads();
    if (tid < 160) {
        const float gvv = uacc / Sred[tid >> 4];
        out[NN * OO + (size_t)n * 160 + tid] = gvv;
        gvl[tid] = gvv;
    }
    __syncthreads();
    if (tid < OO) {
        float g2 = 0.f;
        #pragma unroll
        for (int e = 0; e < 16; ++e) g2 = fmaf(gvl[tid * 16 + e], gvl[tid * 16 + e], g2);
        const float S1 = Sred[tid];
        // sigma = T/(S+EPS) - ||gv||^2*(S+2EPS)/(S+EPS)   (exact coeff-fold algebra)
        float sigma = Tred[tid] / S1 - g2 * (S1 + NEPS) / S1;
        sigma = fmaxf(sigma, 1e-30f);
        const float x = 0.01f * (beta_a[tid] - 0.5f * logf(sigma));
        out[n * OO + tid] = 1.0f / (1.0f + expf(-x));
    }
}

extern "C" void kernel_launch(void* const* d_in, const int* in_sizes, int n_in,
                              void* d_out, int out_size, void* d_ws, size_t ws_size,
                              hipStream_t stream)
{
    const float* l      = (const float*)d_in[0];
    const float* g      = (const float*)d_in[1];
    const float* weight = (const float*)d_in[2];
    const float* beta_a = (const float*)d_in[3];
    float* out = (float*)d_out;
    float* ws  = (float*)d_ws;

    dim3 gA(NN * CC), bA(256);
    accum_kernel<0><<<gA, bA, 0, stream>>>(l, g, weight, ws);
    accum_kernel<1><<<gA, bA, 0, stream>>>(l, g, weight, ws);
    accum_kernel<2><<<gA, bA, 0, stream>>>(l, g, weight, ws);
    finalize_kernel<<<dim3(NN), dim3(256), 0, stream>>>(beta_a, out, ws);
}